// Round 18
// baseline (65.393 us; speedup 1.0000x reference)
//
#include <hip/hip_runtime.h>

#define L_IN   2048
#define C_IN   512
#define L_OUT  2045
#define XT_PAD 21
#define CS     520    // xtile row stride (elems)
#define GP2S   524    // out2 g-pair stride (dwords)

typedef short short8 __attribute__((ext_vector_type(8)));
typedef float float4v __attribute__((ext_vector_type(4)));

__device__ __forceinline__ unsigned short bf16r(float f) {
    unsigned u = __float_as_uint(f);
    unsigned r = (u + 0x7FFFu + ((u >> 16) & 1u)) >> 16;
    return (unsigned short)r;
}

__device__ __forceinline__ unsigned bf16pk(float lo, float hi) {
    return (unsigned)bf16r(lo) | ((unsigned)bf16r(hi) << 16);
}

// raw barrier: LDS producer-visibility only; does NOT drain vmcnt
#define BAR() do { asm volatile("s_waitcnt lgkmcnt(0)" ::: "memory"); \
                   __builtin_amdgcn_s_barrier(); } while (0)

// ---------------- kernel 1: build W21/W43 in MFMA fragment layout (verified R3/R5/R6) ----
__global__ __launch_bounds__(256)
void build_wf(const float* __restrict__ tw, unsigned short* __restrict__ W21f,
              unsigned short* __restrict__ W43f) {
    int id = blockIdx.x * 256 + threadIdx.x;
    if (id < 65536) {
        int p = id & 7, lane = (id >> 3) & 63, oh = (id >> 9) & 1, g = id >> 10;
        int a = oh * 16 + (lane & 15);
        int e = ((lane >> 4) & 3) * 8 + p;
        int r2 = a >> 2, d2 = a & 3, c2 = e >> 2, c1 = e & 3;
        float v = tw[8192 + ((g * 4 + d2) * 8 + r2) * 8 + c2]
                * tw[(g * 8 + c2) * 16 + d2 * 4 + c1];
        W21f[id] = bf16r(v);
    } else if (id < 98304) {
        int id2 = id - 65536;
        int p = id2 & 7, lane = (id2 >> 3) & 63, kh = (id2 >> 9) & 1, s = id2 >> 10;
        int u = lane & 15;
        int w = kh * 32 + ((lane >> 4) & 3) * 8 + p;
        int r4 = u >> 1, hi = u & 1, d4 = hi * 32 + s, p2 = w >> 3, c3 = w & 7;
        float v = 0.f;
        #pragma unroll
        for (int lo = 0; lo < 2; ++lo)
            v += tw[32768 + (d4 * 8 + r4) * 16 + (2 * p2 + lo)]
               * tw[24576 + ((p2 * 32 + s) * 4 + (2 * lo + hi)) * 8 + c3];
        W43f[id2] = bf16r(v);
    }
}

// ---------------- kernel 2: fused two-stage block MFMA, l-tile = 32, split staging -------
// Layouts byte-identical to verified R15. Half-1 x rows (17-34) loaded upfront into regs,
// written to LDS after phase-0's first stage-B (their first reader is A(1,0)).
__global__ __launch_bounds__(512, 4)
void debut_fused_mfma(const unsigned short* __restrict__ W21f,
                      const unsigned short* __restrict__ W43f,
                      const float* __restrict__ x,
                      const float* __restrict__ bias, float* __restrict__ out) {
    __shared__ unsigned short xtile[35 * CS];   // 36400 B
    __shared__ unsigned int   out2[16 * GP2S];  // 33536 B  (total 69936 -> 2 blocks/CU)

    // XCD-aware bijective swizzle (1024 blocks, 8 XCDs, 128 each)
    const int bid = blockIdx.x;
    const int swz = (bid & 7) * 128 + (bid >> 3);
    const int lt = swz & 63, b = swz >> 6;
    const int l0 = lt * 32;
    const int t = threadIdx.x;
    const int lane = t & 63, wv = t >> 6;        // 8 waves
    const int lr = lane & 15, lh = lane >> 4;
    const int lq = t & 3, ccq = t >> 2;

    const float* xb = x + (size_t)b * C_IN * L_IN;

    // ---- 1) half-0 x loads (rows 0-15) + row-16 scalars: needed first ----
    float4 xh0[4];
    #pragma unroll
    for (int pass = 0; pass < 4; ++pass)
        xh0[pass] = *reinterpret_cast<const float4*>(xb + (size_t)(pass * 128 + ccq) * L_IN + l0 + lq * 4);
    float r16[4];
    if (lq == 0) {
        #pragma unroll
        for (int pass = 0; pass < 4; ++pass)
            r16[pass] = xb[(size_t)(pass * 128 + ccq) * L_IN + l0 + 16];
    }

    // ---- 2) phase-0 stage-A weights + stage-B wa (needed after BAR1) ----
    short8 wf[8];   // [k2*4 + q*2 + oh]
    #pragma unroll
    for (int k2 = 0; k2 < 2; ++k2)
        #pragma unroll
        for (int q = 0; q < 2; ++q)
            #pragma unroll
            for (int oh = 0; oh < 2; ++oh) {
                const int g = (wv * 2 + k2) * 2 + q;   // phase-0 global g
                wf[k2 * 4 + q * 2 + oh] =
                    *(const short8*)(W21f + ((size_t)(g * 2 + oh) * 64 + lane) * 8);
            }
    short8 wa[4][2];
    #pragma unroll
    for (int si = 0; si < 4; ++si) {
        int s = wv * 4 + si;
        wa[si][0] = *(const short8*)(W43f + ((size_t)(s * 2 + 0) * 64 + lane) * 8);
        wa[si][1] = *(const short8*)(W43f + ((size_t)(s * 2 + 1) * 64 + lane) * 8);
    }

    // ---- 3) half-1 x loads (rows 16-34): first reader is A(1,0), 3 phases away ----
    float4 xh1[4];
    #pragma unroll
    for (int pass = 0; pass < 4; ++pass)
        xh1[pass] = *reinterpret_cast<const float4*>(xb + (size_t)(pass * 128 + ccq) * L_IN + l0 + 16 + lq * 4);
    float4 xt4;
    {
        int lx = l0 + 32; if (lx > L_IN - 4) lx = L_IN - 4;
        xt4 = *reinterpret_cast<const float4*>(xb + (size_t)t * L_IN + lx);
    }

    // ---- 4) bias prefetch (epilogue-only) ----
    float bv[4][4];
    #pragma unroll
    for (int si = 0; si < 4; ++si)
        #pragma unroll
        for (int i = 0; i < 4; ++i)
            bv[si][i] = bias[wv * 4 + si + 32 * (lh * 4 + i)];

    // ---- XWRITE0: rows 0-15 (+ row 16 from r16) ----
    #pragma unroll
    for (int pass = 0; pass < 4; ++pass) {
        int cc = pass * 128 + ccq;
        int base = (lq * 4) * CS + cc;
        xtile[base         ] = bf16r(xh0[pass].x);
        xtile[base + CS    ] = bf16r(xh0[pass].y);
        xtile[base + 2 * CS] = bf16r(xh0[pass].z);
        xtile[base + 3 * CS] = bf16r(xh0[pass].w);
    }
    if (lq == 0) {
        #pragma unroll
        for (int pass = 0; pass < 4; ++pass)
            xtile[16 * CS + pass * 128 + ccq] = bf16r(r16[pass]);
    }

    BAR();   // xtile rows 0-16 ready; xh1/tail/wf/wa loads still in flight

#define STAGE_A(LH, PH)                                                                  \
    do {                                                                                 \
        const int koff = 2 * (PH) + (wv >> 2);                                           \
        const unsigned short* xrow = &xtile[((LH) * 16 + lr + koff) * CS + lh * 8];      \
        _Pragma("unroll")                                                                \
        for (int k2 = 0; k2 < 2; ++k2) {                                                 \
            const int gp2 = wv * 2 + k2;                                                 \
            float4v accA[2][2];                                                          \
            _Pragma("unroll")                                                            \
            for (int q = 0; q < 2; ++q) {                                                \
                const int gl = gp2 * 2 + q;                                              \
                short8 vfrag = *(const short8*)(xrow + (gl & 15) * 32);                  \
                _Pragma("unroll")                                                        \
                for (int oh = 0; oh < 2; ++oh) {                                         \
                    float4v z = {};                                                      \
                    accA[q][oh] = __builtin_amdgcn_mfma_f32_16x16x32_bf16(               \
                        vfrag, wf[k2 * 4 + q * 2 + oh], z, 0, 0, 0);                     \
                }                                                                        \
            }                                                                            \
            _Pragma("unroll")                                                            \
            for (int oh = 0; oh < 2; ++oh) {                                             \
                const int a = oh * 16 + lr;                                              \
                uint4 w;                                                                 \
                w.x = bf16pk(accA[0][oh][0], accA[1][oh][0]);                            \
                w.y = bf16pk(accA[0][oh][1], accA[1][oh][1]);                            \
                w.z = bf16pk(accA[0][oh][2], accA[1][oh][2]);                            \
                w.w = bf16pk(accA[0][oh][3], accA[1][oh][3]);                            \
                *(uint4*)&out2[gp2 * GP2S + a * 16 + lh * 4] = w;                        \
            }                                                                            \
        }                                                                                \
    } while (0)

#define STAGE_B(ACC, PH)                                                                 \
    do {                                                                                 \
        _Pragma("unroll")                                                                \
        for (int si = 0; si < 4; ++si) {                                                 \
            const int s = wv * 4 + si;                                                   \
            const int rb = s * 16 + lr;                                                  \
            uint4 uw;                                                                    \
            uw.x = out2[(lh * 4 + 0) * GP2S + rb];                                       \
            uw.y = out2[(lh * 4 + 1) * GP2S + rb];                                       \
            uw.z = out2[(lh * 4 + 2) * GP2S + rb];                                       \
            uw.w = out2[(lh * 4 + 3) * GP2S + rb];                                       \
            short8 bb = *reinterpret_cast<short8*>(&uw);                                 \
            ACC[si] = __builtin_amdgcn_mfma_f32_16x16x32_bf16(wa[si][PH], bb, ACC[si], 0, 0, 0); \
        }                                                                                \
    } while (0)

#define LOADWF(PH)                                                                       \
    do {                                                                                 \
        _Pragma("unroll")                                                                \
        for (int k2 = 0; k2 < 2; ++k2)                                                   \
            _Pragma("unroll")                                                            \
            for (int q = 0; q < 2; ++q)                                                  \
                _Pragma("unroll")                                                        \
                for (int oh = 0; oh < 2; ++oh) {                                         \
                    const int g = (PH) * 32 + (wv * 2 + k2) * 2 + q;                     \
                    wf[k2 * 4 + q * 2 + oh] =                                            \
                        *(const short8*)(W21f + ((size_t)(g * 2 + oh) * 64 + lane) * 8); \
                }                                                                        \
    } while (0)

    float4v accB0[4] = {};
    float4v accB1[4] = {};

    // ---- phase p=0 ----
    STAGE_A(0, 0);
    BAR();
    STAGE_B(accB0, 0);

    // XWRITE1: rows 17-31 from xh1 (+ tail rows 32-34) — loads have had ~3 phases to land
    #pragma unroll
    for (int pass = 0; pass < 4; ++pass) {
        int cc = pass * 128 + ccq;
        int base = (16 + lq * 4) * CS + cc;
        if (lq != 0) xtile[base] = bf16r(xh1[pass].x);   // row 16 already written for lq==0
        xtile[base + CS    ] = bf16r(xh1[pass].y);
        xtile[base + 2 * CS] = bf16r(xh1[pass].z);
        xtile[base + 3 * CS] = bf16r(xh1[pass].w);
    }
    xtile[32 * CS + t] = bf16r(xt4.x);
    xtile[33 * CS + t] = bf16r(xt4.y);
    xtile[34 * CS + t] = bf16r(xt4.z);

    BAR();   // rows 17-34 visible before A(1,0)
    STAGE_A(1, 0);
    BAR();
    LOADWF(1);                 // wf(0) dead after A(1,0); loads float to phase-1 use
    STAGE_B(accB1, 0);
    BAR();

    // ---- phase p=1 ----
    STAGE_A(0, 1);
    BAR();
    STAGE_B(accB0, 1);
    BAR();
    STAGE_A(1, 1);
    BAR();
    STAGE_B(accB1, 1);

#undef STAGE_A
#undef STAGE_B
#undef LOADWF

    // ---- store: two adjacent 64B halves per o-row (128B line coverage), prefetched bias --
    const int lpos0 = l0 + lr;
    const int lpos1 = l0 + 16 + lr;
    #pragma unroll
    for (int si = 0; si < 4; ++si) {
        const int s = wv * 4 + si;
        #pragma unroll
        for (int i = 0; i < 4; ++i) {
            int o4 = s + 32 * (lh * 4 + i);
            size_t ro = (size_t)(b * 512 + o4) * L_OUT;
            if (lpos0 < L_OUT) out[ro + lpos0] = accB0[si][i] + bv[si][i];
            if (lpos1 < L_OUT) out[ro + lpos1] = accB1[si][i] + bv[si][i];
        }
    }
}

// ---------------- fallback (round-1 kernel, used if ws too small) ----------------
__global__ __launch_bounds__(256)
void debut_fused_kernel(const float* __restrict__ x,
                        const float* __restrict__ tw,
                        const float* __restrict__ bias,
                        float* __restrict__ out)
{
    __shared__ float xt[C_IN * XT_PAD];
    __shared__ float bufA[2048];
    __shared__ float bufB[2048];
    const int tile = blockIdx.x, b = blockIdx.y;
    const int l0 = tile * 16;
    const int tid = threadIdx.x;
    const float* xb = x + (size_t)b * C_IN * L_IN;
    for (int idx = tid; idx < C_IN * 19; idx += 256) {
        int c = idx / 19, ll = idx - c * 19, l = l0 + ll;
        xt[c * XT_PAD + ll] = (l < L_IN) ? xb[c * L_IN + l] : 0.0f;
    }
    __syncthreads();
    const float* t1 = tw; const float* t2 = tw + 8192;
    const float* t3 = tw + 24576; const float* t4 = tw + 32768;
    for (int rr = 0; rr < 16; ++rr) {
        const int l = l0 + rr;
        if (l >= L_OUT) break;
        #pragma unroll
        for (int i = 0; i < 8; ++i) {
            int o = tid + 256 * i, gb = o >> 2, k = gb >> 7, cb = (gb & 127) << 2;
            const float4 tq = *reinterpret_cast<const float4*>(t1 + o * 4);
            const float* xp = &xt[cb * XT_PAD + rr + k];
            bufA[o] = tq.x * xp[0] + tq.y * xp[XT_PAD] + tq.z * xp[2 * XT_PAD] + tq.w * xp[3 * XT_PAD];
        }
        __syncthreads();
        #pragma unroll
        for (int i = 0; i < 8; ++i) {
            int o = tid + 256 * i, gb = o >> 5, r = (o >> 2) & 7, d = o & 3;
            const float* tp = t2 + (((gb << 2) + d) * 8 + r) * 8;
            const float* ip = &bufA[(gb << 5) + d];
            float acc = 0.0f;
            #pragma unroll
            for (int c = 0; c < 8; ++c) acc += tp[c] * ip[c << 2];
            bufB[o] = acc;
        }
        __syncthreads();
        #pragma unroll
        for (int i = 0; i < 4; ++i) {
            int o = tid + 256 * i, gb = o >> 7, r = (o >> 5) & 3, d = o & 31;
            const float* tp = t3 + (((gb << 5) + d) * 4 + r) * 8;
            const float* ip = &bufB[(gb << 8) + d];
            float acc = 0.0f;
            #pragma unroll
            for (int c = 0; c < 8; ++c) acc += tp[c] * ip[c << 5];
            bufA[o] = acc;
        }
        __syncthreads();
        #pragma unroll
        for (int i = 0; i < 2; ++i) {
            int o = tid + 256 * i, r = o >> 6, d = o & 63;
            const float* tp = t4 + ((d << 3) + r) * 16;
            float acc = 0.0f;
            #pragma unroll
            for (int c = 0; c < 16; ++c) acc += tp[c] * bufA[(c << 6) + d];
            out[((size_t)(b * 512 + o)) * L_OUT + l] = acc + bias[o];
        }
        __syncthreads();
    }
}

extern "C" void kernel_launch(void* const* d_in, const int* in_sizes, int n_in,
                              void* d_out, int out_size, void* d_ws, size_t ws_size,
                              hipStream_t stream) {
    const float* x    = (const float*)d_in[0];
    const float* tw   = (const float*)d_in[1];
    const float* bias = (const float*)d_in[2];
    float* out = (float*)d_out;

    const size_t W21_B = 65536 * 2;      // 128 KB
    const size_t W43_B = 32768 * 2;      // 64 KB

    if (ws_size < W21_B + W43_B) {
        dim3 grid(128, 16);
        debut_fused_kernel<<<grid, dim3(256), 0, stream>>>(x, tw, bias, out);
        return;
    }

    unsigned short* W21f = (unsigned short*)d_ws;
    unsigned short* W43f = (unsigned short*)((char*)d_ws + W21_B);

    build_wf<<<dim3(384), dim3(256), 0, stream>>>(tw, W21f, W43f);
    debut_fused_mfma<<<dim3(1024), dim3(512), 0, stream>>>(W21f, W43f, x, bias, out);
}

// Round 19
// 45.170 us; speedup vs baseline: 1.4477x; 1.4477x over previous
//
#include <hip/hip_runtime.h>

#define L_IN   2048
#define C_IN   512
#define L_OUT  2045
#define XT_PAD 21
#define CS     520    // xtile row stride (elems)
#define GP2S   524    // out2 g-pair stride (dwords)

typedef short short8 __attribute__((ext_vector_type(8)));
typedef float float4v __attribute__((ext_vector_type(4)));

__device__ __forceinline__ unsigned short bf16r(float f) {
    unsigned u = __float_as_uint(f);
    unsigned r = (u + 0x7FFFu + ((u >> 16) & 1u)) >> 16;
    return (unsigned short)r;
}

__device__ __forceinline__ unsigned bf16pk(float lo, float hi) {
    return (unsigned)bf16r(lo) | ((unsigned)bf16r(hi) << 16);
}

// ---------------- kernel 1: build W21/W43 in MFMA fragment layout (verified R3/R5/R6) ----
__global__ __launch_bounds__(256)
void build_wf(const float* __restrict__ tw, unsigned short* __restrict__ W21f,
              unsigned short* __restrict__ W43f) {
    int id = blockIdx.x * 256 + threadIdx.x;
    if (id < 65536) {
        int p = id & 7, lane = (id >> 3) & 63, oh = (id >> 9) & 1, g = id >> 10;
        int a = oh * 16 + (lane & 15);
        int e = ((lane >> 4) & 3) * 8 + p;
        int r2 = a >> 2, d2 = a & 3, c2 = e >> 2, c1 = e & 3;
        float v = tw[8192 + ((g * 4 + d2) * 8 + r2) * 8 + c2]
                * tw[(g * 8 + c2) * 16 + d2 * 4 + c1];
        W21f[id] = bf16r(v);
    } else if (id < 98304) {
        int id2 = id - 65536;
        int p = id2 & 7, lane = (id2 >> 3) & 63, kh = (id2 >> 9) & 1, s = id2 >> 10;
        int u = lane & 15;
        int w = kh * 32 + ((lane >> 4) & 3) * 8 + p;
        int r4 = u >> 1, hi = u & 1, d4 = hi * 32 + s, p2 = w >> 3, c3 = w & 7;
        float v = 0.f;
        #pragma unroll
        for (int lo = 0; lo < 2; ++lo)
            v += tw[32768 + (d4 * 8 + r4) * 16 + (2 * p2 + lo)]
               * tw[24576 + ((p2 * 32 + s) * 4 + (2 * lo + hi)) * 8 + c3];
        W43f[id2] = bf16r(v);
    }
}

// ---------------- kernel 2: fused two-stage block MFMA, register-prefetched weights ------
__global__ __launch_bounds__(512, 4)
void debut_fused_mfma(const unsigned short* __restrict__ W21f,
                      const unsigned short* __restrict__ W43f,
                      const float* __restrict__ x,
                      const float* __restrict__ bias, float* __restrict__ out) {
    __shared__ unsigned short xtile[19 * CS];   // 19760 B
    __shared__ unsigned int   out2[16 * GP2S];  // 33536 B

    // XCD-aware bijective swizzle (2048 blocks, 8 XCDs, 256 each)
    const int bid = blockIdx.x;
    const int swz = (bid & 7) * 256 + (bid >> 3);
    const int lt = swz & 127, b = swz >> 7;
    const int l0 = lt * 16;
    const int t = threadIdx.x;
    const int lane = t & 63, wv = t >> 6;        // 8 waves
    const int lr = lane & 15, lh = lane >> 4;

    const float* xb = x + (size_t)b * C_IN * L_IN;

    // ---- prefetch phase-0 stage-A weights + stage-B wa ----
    short8 wf[8];   // [k2*4 + q*2 + oh]
    #pragma unroll
    for (int k2 = 0; k2 < 2; ++k2)
        #pragma unroll
        for (int q = 0; q < 2; ++q)
            #pragma unroll
            for (int oh = 0; oh < 2; ++oh) {
                const int g = (wv * 2 + k2) * 2 + q;   // phase-0 global g
                wf[k2 * 4 + q * 2 + oh] =
                    *(const short8*)(W21f + ((size_t)(g * 2 + oh) * 64 + lane) * 8);
            }
    short8 wa[4][2];
    #pragma unroll
    for (int si = 0; si < 4; ++si) {
        int s = wv * 4 + si;
        wa[si][0] = *(const short8*)(W43f + ((size_t)(s * 2 + 0) * 64 + lane) * 8);
        wa[si][1] = *(const short8*)(W43f + ((size_t)(s * 2 + 1) * 64 + lane) * 8);
    }

    // ---- stage x: x[b, :, l0..l0+18] -> xtile ----
    {
        const int lq = t & 3;
        #pragma unroll
        for (int pass = 0; pass < 4; ++pass) {
            int cc = pass * 128 + (t >> 2);
            float4 v = *reinterpret_cast<const float4*>(xb + (size_t)cc * L_IN + l0 + lq * 4);
            int base = (lq * 4) * CS + cc;
            xtile[base         ] = bf16r(v.x);
            xtile[base + CS    ] = bf16r(v.y);
            xtile[base + 2 * CS] = bf16r(v.z);
            xtile[base + 3 * CS] = bf16r(v.w);
        }
        int cc = t;
        int lx = l0 + 16; if (lx > L_IN - 4) lx = L_IN - 4;
        float4 v = *reinterpret_cast<const float4*>(xb + (size_t)cc * L_IN + lx);
        int base = 16 * CS + cc;
        xtile[base         ] = bf16r(v.x);
        xtile[base + CS    ] = bf16r(v.y);
        xtile[base + 2 * CS] = bf16r(v.z);
    }

    __syncthreads();   // xtile ready; wf/wa loads drained

    float4v accB[4] = {};

    // =================== phase 0 ===================
    {
        const int koff = 0 + (wv >> 2);
        const unsigned short* xrow = &xtile[(lr + koff) * CS + lh * 8];
        #pragma unroll
        for (int k2 = 0; k2 < 2; ++k2) {
            const int gp2 = wv * 2 + k2;
            float4v accA[2][2];
            #pragma unroll
            for (int q = 0; q < 2; ++q) {
                const int gl = gp2 * 2 + q;
                short8 vfrag = *(const short8*)(xrow + (gl & 15) * 32);
                #pragma unroll
                for (int oh = 0; oh < 2; ++oh) {
                    float4v z = {};
                    accA[q][oh] = __builtin_amdgcn_mfma_f32_16x16x32_bf16(
                        vfrag, wf[k2 * 4 + q * 2 + oh], z, 0, 0, 0);
                }
            }
            #pragma unroll
            for (int oh = 0; oh < 2; ++oh) {
                const int a = oh * 16 + lr;
                uint4 w;
                w.x = bf16pk(accA[0][oh][0], accA[1][oh][0]);
                w.y = bf16pk(accA[0][oh][1], accA[1][oh][1]);
                w.z = bf16pk(accA[0][oh][2], accA[1][oh][2]);
                w.w = bf16pk(accA[0][oh][3], accA[1][oh][3]);
                *(uint4*)&out2[gp2 * GP2S + a * 16 + lh * 4] = w;
            }
        }
        __syncthreads();   // out2 phase-0 ready

        // issue phase-1 stage-A weight loads now; the next barrier drains them
        #pragma unroll
        for (int k2 = 0; k2 < 2; ++k2)
            #pragma unroll
            for (int q = 0; q < 2; ++q)
                #pragma unroll
                for (int oh = 0; oh < 2; ++oh) {
                    const int g = 32 + (wv * 2 + k2) * 2 + q;   // phase-1 global g
                    wf[k2 * 4 + q * 2 + oh] =
                        *(const short8*)(W21f + ((size_t)(g * 2 + oh) * 64 + lane) * 8);
                }

        // stage B phase 0
        #pragma unroll
        for (int si = 0; si < 4; ++si) {
            const int s = wv * 4 + si;
            const int rb = s * 16 + lr;
            uint4 uw;
            uw.x = out2[(lh * 4 + 0) * GP2S + rb];
            uw.y = out2[(lh * 4 + 1) * GP2S + rb];
            uw.z = out2[(lh * 4 + 2) * GP2S + rb];
            uw.w = out2[(lh * 4 + 3) * GP2S + rb];
            short8 bb = *reinterpret_cast<short8*>(&uw);
            accB[si] = __builtin_amdgcn_mfma_f32_16x16x32_bf16(wa[si][0], bb, accB[si], 0, 0, 0);
        }
        __syncthreads();   // stage-B reads done; wf phase-1 drained
    }

    // =================== phase 1 ===================
    {
        const int koff = 2 + (wv >> 2);
        const unsigned short* xrow = &xtile[(lr + koff) * CS + lh * 8];
        #pragma unroll
        for (int k2 = 0; k2 < 2; ++k2) {
            const int gp2 = wv * 2 + k2;
            float4v accA[2][2];
            #pragma unroll
            for (int q = 0; q < 2; ++q) {
                const int gl = gp2 * 2 + q;
                short8 vfrag = *(const short8*)(xrow + (gl & 15) * 32);
                #pragma unroll
                for (int oh = 0; oh < 2; ++oh) {
                    float4v z = {};
                    accA[q][oh] = __builtin_amdgcn_mfma_f32_16x16x32_bf16(
                        vfrag, wf[k2 * 4 + q * 2 + oh], z, 0, 0, 0);
                }
            }
            #pragma unroll
            for (int oh = 0; oh < 2; ++oh) {
                const int a = oh * 16 + lr;
                uint4 w;
                w.x = bf16pk(accA[0][oh][0], accA[1][oh][0]);
                w.y = bf16pk(accA[0][oh][1], accA[1][oh][1]);
                w.z = bf16pk(accA[0][oh][2], accA[1][oh][2]);
                w.w = bf16pk(accA[0][oh][3], accA[1][oh][3]);
                *(uint4*)&out2[gp2 * GP2S + a * 16 + lh * 4] = w;
            }
        }
        __syncthreads();

        #pragma unroll
        for (int si = 0; si < 4; ++si) {
            const int s = wv * 4 + si;
            const int rb = s * 16 + lr;
            uint4 uw;
            uw.x = out2[(lh * 4 + 0) * GP2S + rb];
            uw.y = out2[(lh * 4 + 1) * GP2S + rb];
            uw.z = out2[(lh * 4 + 2) * GP2S + rb];
            uw.w = out2[(lh * 4 + 3) * GP2S + rb];
            short8 bb = *reinterpret_cast<short8*>(&uw);
            accB[si] = __builtin_amdgcn_mfma_f32_16x16x32_bf16(wa[si][1], bb, accB[si], 0, 0, 0);
        }
    }

    // ---- store ----
    const int lpos = l0 + lr;
    if (lpos < L_OUT) {
        #pragma unroll
        for (int si = 0; si < 4; ++si) {
            const int s = wv * 4 + si;
            #pragma unroll
            for (int i = 0; i < 4; ++i) {
                int o4 = s + 32 * (lh * 4 + i);
                out[((size_t)(b * 512 + o4)) * L_OUT + lpos] = accB[si][i] + bias[o4];
            }
        }
    }
}

// ---------------- fallback (round-1 kernel, used if ws too small) ----------------
__global__ __launch_bounds__(256)
void debut_fused_kernel(const float* __restrict__ x,
                        const float* __restrict__ tw,
                        const float* __restrict__ bias,
                        float* __restrict__ out)
{
    __shared__ float xt[C_IN * XT_PAD];
    __shared__ float bufA[2048];
    __shared__ float bufB[2048];
    const int tile = blockIdx.x, b = blockIdx.y;
    const int l0 = tile * 16;
    const int tid = threadIdx.x;
    const float* xb = x + (size_t)b * C_IN * L_IN;
    for (int idx = tid; idx < C_IN * 19; idx += 256) {
        int c = idx / 19, ll = idx - c * 19, l = l0 + ll;
        xt[c * XT_PAD + ll] = (l < L_IN) ? xb[c * L_IN + l] : 0.0f;
    }
    __syncthreads();
    const float* t1 = tw; const float* t2 = tw + 8192;
    const float* t3 = tw + 24576; const float* t4 = tw + 32768;
    for (int rr = 0; rr < 16; ++rr) {
        const int l = l0 + rr;
        if (l >= L_OUT) break;
        #pragma unroll
        for (int i = 0; i < 8; ++i) {
            int o = tid + 256 * i, gb = o >> 2, k = gb >> 7, cb = (gb & 127) << 2;
            const float4 tq = *reinterpret_cast<const float4*>(t1 + o * 4);
            const float* xp = &xt[cb * XT_PAD + rr + k];
            bufA[o] = tq.x * xp[0] + tq.y * xp[XT_PAD] + tq.z * xp[2 * XT_PAD] + tq.w * xp[3 * XT_PAD];
        }
        __syncthreads();
        #pragma unroll
        for (int i = 0; i < 8; ++i) {
            int o = tid + 256 * i, gb = o >> 5, r = (o >> 2) & 7, d = o & 3;
            const float* tp = t2 + (((gb << 2) + d) * 8 + r) * 8;
            const float* ip = &bufA[(gb << 5) + d];
            float acc = 0.0f;
            #pragma unroll
            for (int c = 0; c < 8; ++c) acc += tp[c] * ip[c << 2];
            bufB[o] = acc;
        }
        __syncthreads();
        #pragma unroll
        for (int i = 0; i < 4; ++i) {
            int o = tid + 256 * i, gb = o >> 7, r = (o >> 5) & 3, d = o & 31;
            const float* tp = t3 + (((gb << 5) + d) * 4 + r) * 8;
            const float* ip = &bufB[(gb << 8) + d];
            float acc = 0.0f;
            #pragma unroll
            for (int c = 0; c < 8; ++c) acc += tp[c] * ip[c << 5];
            bufA[o] = acc;
        }
        __syncthreads();
        #pragma unroll
        for (int i = 0; i < 2; ++i) {
            int o = tid + 256 * i, r = o >> 6, d = o & 63;
            const float* tp = t4 + ((d << 3) + r) * 16;
            float acc = 0.0f;
            #pragma unroll
            for (int c = 0; c < 16; ++c) acc += tp[c] * bufA[(c << 6) + d];
            out[((size_t)(b * 512 + o)) * L_OUT + l] = acc + bias[o];
        }
        __syncthreads();
    }
}

extern "C" void kernel_launch(void* const* d_in, const int* in_sizes, int n_in,
                              void* d_out, int out_size, void* d_ws, size_t ws_size,
                              hipStream_t stream) {
    const float* x    = (const float*)d_in[0];
    const float* tw   = (const float*)d_in[1];
    const float* bias = (const float*)d_in[2];
    float* out = (float*)d_out;

    const size_t W21_B = 65536 * 2;      // 128 KB
    const size_t W43_B = 32768 * 2;      // 64 KB

    if (ws_size < W21_B + W43_B) {
        dim3 grid(128, 16);
        debut_fused_kernel<<<grid, dim3(256), 0, stream>>>(x, tw, bias, out);
        return;
    }

    unsigned short* W21f = (unsigned short*)d_ws;
    unsigned short* W43f = (unsigned short*)((char*)d_ws + W21_B);

    build_wf<<<dim3(384), dim3(256), 0, stream>>>(tw, W21f, W43f);
    debut_fused_mfma<<<dim3(2048), dim3(512), 0, stream>>>(W21f, W43f, x, bias, out);
}